// Round 1
// baseline (66.378 us; speedup 1.0000x reference)
//
#include <hip/hip_runtime.h>

#define S_SUB 512
#define T_TR  8192
#define D_IN  8
#define BLOCK 512
#define CHUNK 16   // T_TR / BLOCK

// ---------------------------------------------------------------------------
// Kernel 1: per-subject parameter draws, all in double precision.
//   a  = 0.99 + 0.1 * ndtri(Fa + u_a*(Fb-Fa)),  Fa=Phi(-9.9), Fb=Phi(0.1)
//   b  = mu_x*(1-a); x0 = mu_x + eps_x0; sd = sqrt(sigmasq)
// ndtri via erfcinv + 2 Newton polish steps (solve Phi(z)=p exactly).
// ---------------------------------------------------------------------------
__global__ void setup_kernel(const float* __restrict__ u_a,
                             const float* __restrict__ sigmasq,
                             const float* __restrict__ eps_mu,
                             const float* __restrict__ eps_x0,
                             double* __restrict__ params) {
    int s = blockIdx.x * blockDim.x + threadIdx.x;
    if (s >= S_SUB) return;
    const double RS2 = 0.7071067811865476;     // 1/sqrt(2)
    const double S2  = 1.4142135623730951;     // sqrt(2)
    const double INV_SQRT_2PI = 0.3989422804014327;

    double Fa = 0.5 * erfc(9.9 * RS2);         // Phi(-9.9)
    double Fb = 0.5 * erfc(-0.1 * RS2);        // Phi(0.1)
    double p  = Fa + (double)u_a[s] * (Fb - Fa);
    double z  = -S2 * erfcinv(2.0 * p);        // ndtri(p)
    // Newton polish: f(z) = Phi(z) - p
    #pragma unroll
    for (int it = 0; it < 2; ++it) {
        double F   = 0.5 * erfc(-z * RS2);
        double pdf = exp(-0.5 * z * z) * INV_SQRT_2PI;
        z -= (F - p) / pdf;
    }
    double a  = 0.99 + 0.1 * z;
    double mu = (double)eps_mu[s];             // SIGMA_MU_X = 1
    double b  = mu * (1.0 - a);
    double x0 = mu + (double)eps_x0[s];        // sqrt(SIGMASQ0) = 1
    double sd = sqrt((double)sigmasq[s]);
    params[4*s+0] = a;
    params[4*s+1] = b;
    params[4*s+2] = sd;
    params[4*s+3] = x0;
}

// ---------------------------------------------------------------------------
// Kernel 2: fused parallel scan + logits + Bernoulli sample.
// One block per subject. Linear recurrence x_{t+1} = a x_t + c_t parallelized
// as an affine-map block scan (Hillis-Steele in LDS, double precision).
// Phase 3 replays the chunk, fusing the D=8 dot product and the sigmoid
// decision (u*(1+exp(-L)) < 1  <=>  u < sigmoid(L)).
// ---------------------------------------------------------------------------
__global__ __launch_bounds__(BLOCK) void lds_kernel(
    const float* __restrict__ inputs,
    const float* __restrict__ eps_w,
    const float* __restrict__ eps_x,
    const float* __restrict__ u_bern,
    const double* __restrict__ params,
    float* __restrict__ out_x,
    float* __restrict__ out_y) {

    const int s   = blockIdx.x;
    const int tid = threadIdx.x;

    __shared__ double sA[BLOCK];
    __shared__ double sB[BLOCK];
    __shared__ double sw[D_IN];

    const double a  = params[4*s+0];
    const double b  = params[4*s+1];
    const double sd = params[4*s+2];
    const double x0 = params[4*s+3];

    if (tid < D_IN) sw[tid] = (double)eps_w[s*D_IN + tid];   // w = eps_w (mu_w=0, sigma_w=1)

    const size_t base = (size_t)s * T_TR + (size_t)tid * CHUNK;

    // ---- load this thread's eps_x chunk (vectorized), keep in registers ----
    float ev[CHUNK];
    {
        const float4* e4 = (const float4*)(eps_x + base);
        #pragma unroll
        for (int q = 0; q < CHUNK/4; ++q) {
            float4 v = e4[q];
            ev[4*q+0] = v.x; ev[4*q+1] = v.y; ev[4*q+2] = v.z; ev[4*q+3] = v.w;
        }
    }

    // ---- phase 1: local affine composition over the chunk ----
    double A = 1.0, Bv = 0.0;
    #pragma unroll
    for (int j = 0; j < CHUNK; ++j) {
        double c = fma(sd, (double)ev[j], b);   // c_t = b + sd*eps
        Bv = fma(a, Bv, c);
        A *= a;
    }

    // ---- phase 2: inclusive block scan of affine maps (Hillis-Steele) ----
    sA[tid] = A; sB[tid] = Bv;
    __syncthreads();
    for (int off = 1; off < BLOCK; off <<= 1) {
        double pA = 0.0, pB = 0.0;
        const bool act = (tid >= off);
        if (act) { pA = sA[tid-off]; pB = sB[tid-off]; }
        __syncthreads();
        if (act) {
            Bv = fma(A, pB, Bv);    // compose: cur ∘ prev
            A  = A * pA;
            sA[tid] = A; sB[tid] = Bv;
        }
        __syncthreads();
    }

    // exclusive prefix -> x at start of this thread's chunk
    double x = x0;
    if (tid > 0) x = fma(sA[tid-1], x0, sB[tid-1]);

    const double w0 = sw[0], w1 = sw[1], w2 = sw[2], w3 = sw[3];
    const double w4 = sw[4], w5 = sw[5], w6 = sw[6], w7 = sw[7];

    // ---- phase 3: replay chunk, fuse logits + Bernoulli ----
    float ubv[CHUNK];
    {
        const float4* u4 = (const float4*)(u_bern + base);
        #pragma unroll
        for (int q = 0; q < CHUNK/4; ++q) {
            float4 v = u4[q];
            ubv[4*q+0] = v.x; ubv[4*q+1] = v.y; ubv[4*q+2] = v.z; ubv[4*q+3] = v.w;
        }
    }

    const float4* in4 = (const float4*)(inputs + base * D_IN);
    float xv[CHUNK], yv[CHUNK];
    #pragma unroll
    for (int j = 0; j < CHUNK; ++j) {
        float4 i0 = in4[2*j];
        float4 i1 = in4[2*j+1];
        double dot = fma((double)i0.x, w0,
                     fma((double)i0.y, w1,
                     fma((double)i0.z, w2,
                     fma((double)i0.w, w3,
                     fma((double)i1.x, w4,
                     fma((double)i1.y, w5,
                     fma((double)i1.z, w6, (double)i1.w * w7)))))));
        double L = x + dot;
        double E = exp(-L);
        // u < 1/(1+E)  <=>  u*(1+E) < 1
        yv[j] = ((double)ubv[j] * (1.0 + E) < 1.0) ? 1.0f : 0.0f;
        xv[j] = (float)x;                        // output BEFORE update (x_0..x_{T-1})
        double c = fma(sd, (double)ev[j], b);
        x = fma(a, x, c);
    }

    // ---- vectorized stores ----
    float4* ox4 = (float4*)(out_x + base);
    float4* oy4 = (float4*)(out_y + base);
    #pragma unroll
    for (int q = 0; q < CHUNK/4; ++q) {
        ox4[q] = make_float4(xv[4*q+0], xv[4*q+1], xv[4*q+2], xv[4*q+3]);
        oy4[q] = make_float4(yv[4*q+0], yv[4*q+1], yv[4*q+2], yv[4*q+3]);
    }
}

extern "C" void kernel_launch(void* const* d_in, const int* in_sizes, int n_in,
                              void* d_out, int out_size, void* d_ws, size_t ws_size,
                              hipStream_t stream) {
    const float* inputs  = (const float*)d_in[0];   // [S,T,D]
    const float* eps_w   = (const float*)d_in[1];   // [S,D]
    const float* u_a     = (const float*)d_in[2];   // [S]
    const float* sigmasq = (const float*)d_in[3];   // [S]
    const float* eps_mu  = (const float*)d_in[4];   // [S]
    const float* eps_x0  = (const float*)d_in[5];   // [S]
    const float* eps_x   = (const float*)d_in[6];   // [S,T]
    const float* u_bern  = (const float*)d_in[7];   // [S,T]

    float*  out    = (float*)d_out;                 // [x (S*T) | y (S*T)] as f32
    double* params = (double*)d_ws;                 // 4 doubles per subject (16 KiB)

    setup_kernel<<<1, S_SUB, 0, stream>>>(u_a, sigmasq, eps_mu, eps_x0, params);
    lds_kernel<<<S_SUB, BLOCK, 0, stream>>>(inputs, eps_w, eps_x, u_bern, params,
                                            out, out + (size_t)S_SUB * T_TR);
}

// Round 2
// 55.304 us; speedup vs baseline: 1.2002x; 1.2002x over previous
//
#include <hip/hip_runtime.h>

#define S_SUB 512
#define T_TR  8192
#define D_IN  8
#define NSEG  4            // segments per subject
#define SEGT  (T_TR/NSEG)  // 2048 trials per segment
#define BLK   256          // threads per block
#define CH    (SEGT/BLK)   // 8 trials per thread

// ---------------------------------------------------------------------------
// Kernel 1: per-subject parameter draws, double precision.
//   a = 0.99 + 0.1*ndtri(Fa + u_a*(Fb-Fa));  b = mu_x*(1-a); x0 = mu_x+eps_x0
// ndtri via erfcinv + 2 Newton polish steps.
// ---------------------------------------------------------------------------
__global__ void setup_kernel(const float* __restrict__ u_a,
                             const float* __restrict__ sigmasq,
                             const float* __restrict__ eps_mu,
                             const float* __restrict__ eps_x0,
                             double* __restrict__ params) {
    int s = blockIdx.x * blockDim.x + threadIdx.x;
    if (s >= S_SUB) return;
    const double RS2 = 0.7071067811865476;
    const double S2  = 1.4142135623730951;
    const double INV_SQRT_2PI = 0.3989422804014327;

    double Fa = 0.5 * erfc(9.9 * RS2);         // Phi(-9.9)
    double Fb = 0.5 * erfc(-0.1 * RS2);        // Phi(0.1)
    double p  = Fa + (double)u_a[s] * (Fb - Fa);
    double z  = -S2 * erfcinv(2.0 * p);
    #pragma unroll
    for (int it = 0; it < 2; ++it) {
        double F   = 0.5 * erfc(-z * RS2);
        double pdf = exp(-0.5 * z * z) * INV_SQRT_2PI;
        z -= (F - p) / pdf;
    }
    double a  = 0.99 + 0.1 * z;
    double mu = (double)eps_mu[s];
    double b  = mu * (1.0 - a);
    double x0 = mu + (double)eps_x0[s];
    double sd = sqrt((double)sigmasq[s]);
    params[4*s+0] = a;
    params[4*s+1] = b;
    params[4*s+2] = sd;
    params[4*s+3] = x0;
}

// ---------------------------------------------------------------------------
// Kernel 2: per-(subject,segment) affine compose of the AR(1) recurrence.
// x_{t+1} = a x_t + (b + sd*eps_t). Segment map = (A_seg, B_seg).
// One block per (s,seg); per-thread compose over 8 trials, then an in-block
// Hillis-Steele scan; thread 255 holds the full segment compose.
// ---------------------------------------------------------------------------
__global__ __launch_bounds__(BLK) void compose_kernel(
    const float* __restrict__ eps_x,
    const double* __restrict__ params,
    double2* __restrict__ comp) {     // [NSEG][S]

    const int s   = blockIdx.x >> 2;
    const int seg = blockIdx.x & (NSEG - 1);
    const int tid = threadIdx.x;

    const double a  = params[4*s+0];
    const double b  = params[4*s+1];
    const double sd = params[4*s+2];

    const size_t base = (size_t)s * T_TR + (size_t)seg * SEGT + (size_t)tid * CH;

    float ev[CH];
    {
        const float4* e4 = (const float4*)(eps_x + base);
        #pragma unroll
        for (int q = 0; q < CH/4; ++q) {
            float4 v = e4[q];
            ev[4*q+0] = v.x; ev[4*q+1] = v.y; ev[4*q+2] = v.z; ev[4*q+3] = v.w;
        }
    }

    double A = 1.0, Bv = 0.0;
    #pragma unroll
    for (int j = 0; j < CH; ++j) {
        double c = fma(sd, (double)ev[j], b);
        Bv = fma(a, Bv, c);
        A *= a;
    }

    __shared__ double sA[BLK];
    __shared__ double sB[BLK];
    sA[tid] = A; sB[tid] = Bv;
    __syncthreads();
    for (int off = 1; off < BLK; off <<= 1) {
        double pA = 0.0, pB = 0.0;
        const bool act = (tid >= off);
        if (act) { pA = sA[tid-off]; pB = sB[tid-off]; }
        __syncthreads();
        if (act) {
            Bv = fma(A, pB, Bv);
            A  = A * pA;
            sA[tid] = A; sB[tid] = Bv;
        }
        __syncthreads();
    }

    if (tid == BLK - 1) comp[seg * S_SUB + s] = make_double2(A, Bv);
}

// ---------------------------------------------------------------------------
// Kernel 3: chain the NSEG segment composes per subject -> x at segment start.
// One thread per subject; reads/writes coalesced ([seg][s] layout).
// ---------------------------------------------------------------------------
__global__ void seed_kernel(const double* __restrict__ params,
                            const double2* __restrict__ comp,
                            double* __restrict__ seeds) {   // [NSEG][S]
    int s = blockIdx.x * blockDim.x + threadIdx.x;
    if (s >= S_SUB) return;
    double x = params[4*s+3];                 // x0
    #pragma unroll
    for (int seg = 0; seg < NSEG; ++seg) {
        seeds[seg * S_SUB + s] = x;
        double2 c = comp[seg * S_SUB + s];
        x = fma(c.x, x, c.y);
    }
}

// ---------------------------------------------------------------------------
// Kernel 4: fused per-segment scan + replay + logits + Bernoulli.
// One block per (s,seg); independent blocks -> full occupancy streaming.
// Same f64 math as the validated round-1 kernel (bit-identical outputs).
// ---------------------------------------------------------------------------
__global__ __launch_bounds__(BLK) void fused_kernel(
    const float* __restrict__ inputs,
    const float* __restrict__ eps_w,
    const float* __restrict__ eps_x,
    const float* __restrict__ u_bern,
    const double* __restrict__ params,
    const double* __restrict__ seeds,
    float* __restrict__ out_x,
    float* __restrict__ out_y) {

    const int s   = blockIdx.x >> 2;
    const int seg = blockIdx.x & (NSEG - 1);
    const int tid = threadIdx.x;

    __shared__ double sA[BLK];
    __shared__ double sB[BLK];
    __shared__ double sw[D_IN];

    const double a  = params[4*s+0];
    const double b  = params[4*s+1];
    const double sd = params[4*s+2];

    if (tid < D_IN) sw[tid] = (double)eps_w[s*D_IN + tid];

    const size_t base = (size_t)s * T_TR + (size_t)seg * SEGT + (size_t)tid * CH;

    float ev[CH];
    {
        const float4* e4 = (const float4*)(eps_x + base);
        #pragma unroll
        for (int q = 0; q < CH/4; ++q) {
            float4 v = e4[q];
            ev[4*q+0] = v.x; ev[4*q+1] = v.y; ev[4*q+2] = v.z; ev[4*q+3] = v.w;
        }
    }

    // phase 1: local affine compose
    double A = 1.0, Bv = 0.0;
    #pragma unroll
    for (int j = 0; j < CH; ++j) {
        double c = fma(sd, (double)ev[j], b);
        Bv = fma(a, Bv, c);
        A *= a;
    }

    // phase 2: in-block inclusive scan of affine maps
    sA[tid] = A; sB[tid] = Bv;
    __syncthreads();
    for (int off = 1; off < BLK; off <<= 1) {
        double pA = 0.0, pB = 0.0;
        const bool act = (tid >= off);
        if (act) { pA = sA[tid-off]; pB = sB[tid-off]; }
        __syncthreads();
        if (act) {
            Bv = fma(A, pB, Bv);
            A  = A * pA;
            sA[tid] = A; sB[tid] = Bv;
        }
        __syncthreads();
    }

    // x at start of this thread's chunk
    const double xseed = seeds[seg * S_SUB + s];
    double x = xseed;
    if (tid > 0) x = fma(sA[tid-1], xseed, sB[tid-1]);

    const double w0 = sw[0], w1 = sw[1], w2 = sw[2], w3 = sw[3];
    const double w4 = sw[4], w5 = sw[5], w6 = sw[6], w7 = sw[7];

    float ubv[CH];
    {
        const float4* u4 = (const float4*)(u_bern + base);
        #pragma unroll
        for (int q = 0; q < CH/4; ++q) {
            float4 v = u4[q];
            ubv[4*q+0] = v.x; ubv[4*q+1] = v.y; ubv[4*q+2] = v.z; ubv[4*q+3] = v.w;
        }
    }

    // phase 3: replay chunk, fuse logits + Bernoulli
    const float4* in4 = (const float4*)(inputs + base * D_IN);
    float xv[CH], yv[CH];
    #pragma unroll
    for (int j = 0; j < CH; ++j) {
        float4 i0 = in4[2*j];
        float4 i1 = in4[2*j+1];
        double dot = fma((double)i0.x, w0,
                     fma((double)i0.y, w1,
                     fma((double)i0.z, w2,
                     fma((double)i0.w, w3,
                     fma((double)i1.x, w4,
                     fma((double)i1.y, w5,
                     fma((double)i1.z, w6, (double)i1.w * w7)))))));
        double L = x + dot;
        double E = exp(-L);
        yv[j] = ((double)ubv[j] * (1.0 + E) < 1.0) ? 1.0f : 0.0f;
        xv[j] = (float)x;
        double c = fma(sd, (double)ev[j], b);
        x = fma(a, x, c);
    }

    float4* ox4 = (float4*)(out_x + base);
    float4* oy4 = (float4*)(out_y + base);
    #pragma unroll
    for (int q = 0; q < CH/4; ++q) {
        ox4[q] = make_float4(xv[4*q+0], xv[4*q+1], xv[4*q+2], xv[4*q+3]);
        oy4[q] = make_float4(yv[4*q+0], yv[4*q+1], yv[4*q+2], yv[4*q+3]);
    }
}

extern "C" void kernel_launch(void* const* d_in, const int* in_sizes, int n_in,
                              void* d_out, int out_size, void* d_ws, size_t ws_size,
                              hipStream_t stream) {
    const float* inputs  = (const float*)d_in[0];   // [S,T,D]
    const float* eps_w   = (const float*)d_in[1];   // [S,D]
    const float* u_a     = (const float*)d_in[2];   // [S]
    const float* sigmasq = (const float*)d_in[3];   // [S]
    const float* eps_mu  = (const float*)d_in[4];   // [S]
    const float* eps_x0  = (const float*)d_in[5];   // [S]
    const float* eps_x   = (const float*)d_in[6];   // [S,T]
    const float* u_bern  = (const float*)d_in[7];   // [S,T]

    float* out = (float*)d_out;                     // [x | y] f32

    double*  params = (double*)d_ws;                          // 16 KiB
    double2* comp   = (double2*)((char*)d_ws + 16*1024);      // 32 KiB
    double*  seeds  = (double*)((char*)d_ws + 48*1024);       // 16 KiB

    setup_kernel<<<1, S_SUB, 0, stream>>>(u_a, sigmasq, eps_mu, eps_x0, params);
    compose_kernel<<<S_SUB*NSEG, BLK, 0, stream>>>(eps_x, params, comp);
    seed_kernel<<<2, 256, 0, stream>>>(params, comp, seeds);
    fused_kernel<<<S_SUB*NSEG, BLK, 0, stream>>>(inputs, eps_w, eps_x, u_bern,
                                                 params, seeds,
                                                 out, out + (size_t)S_SUB * T_TR);
}